// Round 10
// baseline (348.869 us; speedup 1.0000x reference)
//
#include <hip/hip_runtime.h>
#include <math.h>

static constexpr int Zc  = 64;
static constexpr int Xc  = 32;
static constexpr int Bc  = 4096;
static constexpr int Tc  = 256;

__device__ __forceinline__ float sigf(float x) {
  float e = __expf(-x);
  return __builtin_amdgcn_rcpf(1.0f + e);
}
__device__ __forceinline__ float tanh_fast(float x) {
  float xc = fminf(fmaxf(x, -15.0f), 15.0f);
  float e  = __expf(-2.0f * xc);
  return (1.0f - e) * __builtin_amdgcn_rcpf(1.0f + e);
}
__device__ __forceinline__ float dot4(float4 w, float4 v) {
  return fmaf(w.x, v.x, fmaf(w.y, v.y, fmaf(w.z, v.z, w.w * v.w)));
}
__device__ __forceinline__ float4 ld4(const float* p) { return *(const float4*)p; }

// DPP lane moves: 0xB1=xor1(quad_perm 1,0,3,2), 0x4E=xor2(2,3,0,1),
// 0x141=row_half_mirror (lane i <-> 7-i within 8-lane half-rows).
template <int CTRL>
__device__ __forceinline__ float dppmov(float x) {
  return __int_as_float(
      __builtin_amdgcn_update_dpp(0, __float_as_int(x), CTRL, 0xF, 0xF, true));
}
__device__ __forceinline__ float red8(float x) {
  x += dppmov<0xB1>(x);
  x += dppmov<0x4E>(x);
  x += dppmov<0x141>(x);
  return x;
}
__device__ __forceinline__ float red4(float x) {
  x += dppmov<0xB1>(x);
  x += dppmov<0x4E>(x);
  return x;
}

// LDS-only barrier (global z-store stays in flight; vmcnt never drained in-loop)
__device__ __forceinline__ void bar_lds() {
  asm volatile("s_waitcnt lgkmcnt(0)" ::: "memory");
  __builtin_amdgcn_s_barrier();
  asm volatile("" ::: "memory");
}

// chunk-padded state layout: element k at [k + 4*(k>>4)] -> the 8 possible
// 16-float chunks of a 64-vector start at 20c floats = distinct banks.
#define PADIDX(k) ((k) + 4 * ((k) >> 4))

// 1 block x 512 threads (8 waves), 3 lgkm-barriers/step, DS-inst-minimized.
// amdgpu_waves_per_eu(2): tells the register allocator the kernel only needs
// 2 waves/EU occupancy -> 256-VGPR budget, so ALL 28-32 named float4 weight
// regs stay live across the loop (R8 at default budget: VGPR_Count=96 < the
// ~160 needed -> compiler sank weight loads into the loop = L2 refetch/step).
__global__ __launch_bounds__(512) __attribute__((amdgpu_waves_per_eu(2)))
void chain_kernel(
    const float* __restrict__ z0, const float* __restrict__ h0,
    const float* __restrict__ W_ih, const float* __restrict__ W_hh,
    const float* __restrict__ b_ih, const float* __restrict__ b_hh,
    const float* __restrict__ W_gzh, const float* __restrict__ b_gzh,
    const float* __restrict__ W_ghz, const float* __restrict__ b_ghz,
    const float* __restrict__ W_pzh, const float* __restrict__ b_pzh,
    const float* __restrict__ W_phz, const float* __restrict__ b_phz,
    const float* __restrict__ W_zloc, const float* __restrict__ b_zloc,
    float* __restrict__ zout) {
  const int tid  = threadIdx.x;
  const bool gB  = (tid >= 256);
  const int idx  = tid & 255;

  __shared__ __align__(16) float S[640];
  float* zP  = S;
  float* hPA = S + 80;
  float* hPB = S + 176;
  float* aP  = S + 256;
  float* cP  = S + 416;
  float* zlb = S + 576;

  float4 W00{},W01{},W02{},W03{},W04{},W05{},W06{},W07{},
         W08{},W09{},W10{},W11{},W12{},W13{},W14{},W15{},
         W16{},W17{},W18{},W19{},W20{},W21{},W22{},W23{},
         W24{},W25{},W26{},W27{},W28{},W29{},W30{},W31{};
  float b0=0,b1=0,b2=0,b3=0,b4=0,b5=0,b6=0,b7=0,b8=0;
  float hp0=0, hp1=0;

  const int p  = idx >> 3, c  = idx & 7;    // A:P1  B:P3
  const int jz = idx >> 2, cz = idx & 3;    // A:zl
  const int q  = idx >> 2, ch = idx & 3;    // B:P2
  const int j0 = 2 * p, j1 = 2 * p + 1;
  const int o  = 4 * q + ch;
  float* p2dst = nullptr;

  // ---------------- staging ----------------
  if (!gB) {
    const float* Ws = (c < 4) ? W_ih : W_hh;
    const int col = (c & 3) * 16;
    const float* r0p = Ws + (j0)       * 64 + col;
    const float* u0p = Ws + (64 + j0)  * 64 + col;
    const float* n0p = Ws + (128 + j0) * 64 + col;
    const float* r1p = Ws + (j1)       * 64 + col;
    const float* u1p = Ws + (64 + j1)  * 64 + col;
    const float* n1p = Ws + (128 + j1) * 64 + col;
    W00=ld4(r0p); W01=ld4(r0p+4); W02=ld4(r0p+8); W03=ld4(r0p+12);
    W04=ld4(u0p); W05=ld4(u0p+4); W06=ld4(u0p+8); W07=ld4(u0p+12);
    W08=ld4(n0p); W09=ld4(n0p+4); W10=ld4(n0p+8); W11=ld4(n0p+12);
    W12=ld4(r1p); W13=ld4(r1p+4); W14=ld4(r1p+8); W15=ld4(r1p+12);
    W16=ld4(u1p); W17=ld4(u1p+4); W18=ld4(u1p+8); W19=ld4(u1p+12);
    W20=ld4(n1p); W21=ld4(n1p+4); W22=ld4(n1p+8); W23=ld4(n1p+12);
    const float* zp = W_zloc + jz * 64 + cz * 16;
    W24=ld4(zp); W25=ld4(zp+4); W26=ld4(zp+8); W27=ld4(zp+12);
    b0 = b_ih[j0] + b_hh[j0];
    b1 = b_ih[64 + j0] + b_hh[64 + j0];
    b2 = b_ih[128 + j0];
    b3 = b_hh[128 + j0];
    b4 = b_ih[j1] + b_hh[j1];
    b5 = b_ih[64 + j1] + b_hh[64 + j1];
    b6 = b_ih[128 + j1];
    b7 = b_hh[128 + j1];
    b8 = b_zloc[jz];
    hp0 = h0[j0];
    hp1 = h0[j1];
  } else {
    const bool gz = (q < 32);
    const float* M = gz ? W_gzh : W_pzh;
    const int rb = gz ? 4 * q : 4 * q - 128;
    const float* r0p = M + (rb + 0) * 64 + ch * 16;
    const float* r1p = M + (rb + 1) * 64 + ch * 16;
    const float* r2p = M + (rb + 2) * 64 + ch * 16;
    const float* r3p = M + (rb + 3) * 64 + ch * 16;
    W00=ld4(r0p); W01=ld4(r0p+4); W02=ld4(r0p+8); W03=ld4(r0p+12);
    W04=ld4(r1p); W05=ld4(r1p+4); W06=ld4(r1p+8); W07=ld4(r1p+12);
    W08=ld4(r2p); W09=ld4(r2p+4); W10=ld4(r2p+8); W11=ld4(r2p+12);
    W12=ld4(r3p); W13=ld4(r3p+4); W14=ld4(r3p+8); W15=ld4(r3p+12);
    const float* ga = W_ghz + j0 * 128 + c * 16;
    const float* gb = W_ghz + j1 * 128 + c * 16;
    const float* pa = W_phz + j0 * 128 + c * 16;
    const float* pb = W_phz + j1 * 128 + c * 16;
    W16=ld4(ga); W17=ld4(ga+4); W18=ld4(ga+8); W19=ld4(ga+12);
    W20=ld4(gb); W21=ld4(gb+4); W22=ld4(gb+8); W23=ld4(gb+12);
    W24=ld4(pa); W25=ld4(pa+4); W26=ld4(pa+8); W27=ld4(pa+12);
    W28=ld4(pb); W29=ld4(pb+4); W30=ld4(pb+8); W31=ld4(pb+12);
    b0 = gz ? b_gzh[o] : b_pzh[o - 128];
    b1 = b_ghz[j0];
    b2 = b_ghz[j1];
    b3 = b_phz[j0];
    b4 = b_phz[j1];
    p2dst = gz ? (aP + PADIDX(o)) : (cP + PADIDX(o - 128));
  }

  if (tid < 64) {
    zP[PADIDX(tid)]  = z0[tid];
    hPA[PADIDX(tid)] = h0[tid];
  }
  __syncthreads();

  for (int t = 0; t < Tc; ++t) {
    float* hold = (t & 1) ? hPB : hPA;
    float* hnew = (t & 1) ? hPA : hPB;

    // ---- P1: GRU (group A) ----
    if (!gB) {
      const float* x = ((c < 4) ? zP : hold) + 20 * (c & 3);
      float4 x0 = ld4(x), x1 = ld4(x + 4), x2 = ld4(x + 8), x3 = ld4(x + 12);
      float pr0 = dot4(W00,x0)+dot4(W01,x1)+dot4(W02,x2)+dot4(W03,x3);
      float pu0 = dot4(W04,x0)+dot4(W05,x1)+dot4(W06,x2)+dot4(W07,x3);
      float pn0 = dot4(W08,x0)+dot4(W09,x1)+dot4(W10,x2)+dot4(W11,x3);
      float pr1 = dot4(W12,x0)+dot4(W13,x1)+dot4(W14,x2)+dot4(W15,x3);
      float pu1 = dot4(W16,x0)+dot4(W17,x1)+dot4(W18,x2)+dot4(W19,x3);
      float pn1 = dot4(W20,x0)+dot4(W21,x1)+dot4(W22,x2)+dot4(W23,x3);
      pr0 = red8(pr0); pu0 = red8(pu0);
      pr1 = red8(pr1); pu1 = red8(pu1);
      pn0 += dppmov<0xB1>(pn0); pn0 += dppmov<0x4E>(pn0);
      float pno0 = dppmov<0x141>(pn0);
      pn1 += dppmov<0xB1>(pn1); pn1 += dppmov<0x4E>(pn1);
      float pno1 = dppmov<0x141>(pn1);
      const bool zi = (c < 4);
      float in0 = (zi ? pn0 : pno0) + b2, hn0 = (zi ? pno0 : pn0) + b3;
      float in1 = (zi ? pn1 : pno1) + b6, hn1 = (zi ? pno1 : pn1) + b7;
      float r0 = sigf(pr0 + b0), u0 = sigf(pu0 + b1);
      float r1 = sigf(pr1 + b4), u1 = sigf(pu1 + b5);
      float nn0 = tanh_fast(in0 + r0 * hn0);
      float nn1 = tanh_fast(in1 + r1 * hn1);
      float hv0 = (1.f - u0) * nn0 + u0 * hp0;
      float hv1 = (1.f - u1) * nn1 + u1 * hp1;
      hp0 = hv0; hp1 = hv1;
      if (c < 2) {
        int js = (c == 0) ? j0 : j1;
        hnew[PADIDX(js)] = (c == 0) ? hv0 : hv1;
      }
    }
    bar_lds();

    // ---- P2: gzh/pzh hiddens (group B) || zloc GEMV (group A) ----
    if (gB) {
      const float* x = hnew + 20 * ch;
      float4 x0 = ld4(x), x1 = ld4(x + 4), x2 = ld4(x + 8), x3 = ld4(x + 12);
      float s0 = dot4(W00,x0)+dot4(W01,x1)+dot4(W02,x2)+dot4(W03,x3);
      float s1 = dot4(W04,x0)+dot4(W05,x1)+dot4(W06,x2)+dot4(W07,x3);
      float s2 = dot4(W08,x0)+dot4(W09,x1)+dot4(W10,x2)+dot4(W11,x3);
      float s3 = dot4(W12,x0)+dot4(W13,x1)+dot4(W14,x2)+dot4(W15,x3);
      s0 = red4(s0); s1 = red4(s1); s2 = red4(s2); s3 = red4(s3);
      float own = (ch == 0) ? s0 : (ch == 1) ? s1 : (ch == 2) ? s2 : s3;
      *p2dst = fmaxf(own + b0, 0.f);
    } else {
      const float* x = hnew + 20 * cz;
      float4 x0 = ld4(x), x1 = ld4(x + 4), x2 = ld4(x + 8), x3 = ld4(x + 12);
      float zv = dot4(W24,x0)+dot4(W25,x1)+dot4(W26,x2)+dot4(W27,x3);
      zv = red4(zv);
      if (cz == 0) zlb[jz] = zv + b8;
    }
    bar_lds();

    // ---- P3: gate + pm + z combine (group B) ----
    if (gB) {
      const float* xa = aP + 20 * c;
      const float* xc = cP + 20 * c;
      float4 a0 = ld4(xa), a1 = ld4(xa + 4), a2 = ld4(xa + 8), a3 = ld4(xa + 12);
      float4 c0 = ld4(xc), c1 = ld4(xc + 4), c2 = ld4(xc + 8), c3v = ld4(xc + 12);
      float sg0 = dot4(W16,a0)+dot4(W17,a1)+dot4(W18,a2)+dot4(W19,a3);
      float sg1 = dot4(W20,a0)+dot4(W21,a1)+dot4(W22,a2)+dot4(W23,a3);
      float sp0 = dot4(W24,c0)+dot4(W25,c1)+dot4(W26,c2)+dot4(W27,c3v);
      float sp1 = dot4(W28,c0)+dot4(W29,c1)+dot4(W30,c2)+dot4(W31,c3v);
      sg0 = red8(sg0); sg1 = red8(sg1);
      sp0 = red8(sp0); sp1 = red8(sp1);
      const bool sel1 = (c == 1);
      int js = sel1 ? j1 : j0;
      float zlv = zlb[js];
      float g  = sigf((sel1 ? sg1 : sg0) + (sel1 ? b2 : b1));
      float pm = (sel1 ? sp1 : sp0) + (sel1 ? b4 : b3);
      float z  = (1.f - g) * zlv + g * pm;
      if (c < 2) {
        zP[PADIDX(js)] = z;
        zout[(size_t)t * 64 + js] = z;
      }
    }
    bar_lds();
  }
}

// Observation head: fully parallel over t (one 64-thread block per t).
__global__ __launch_bounds__(64) void obs_kernel(
    const float* __restrict__ zseq,
    const float* __restrict__ W_olh, const float* __restrict__ b_olh,
    const float* __restrict__ W_olx, const float* __restrict__ b_olx,
    const float* __restrict__ W_osh, const float* __restrict__ b_osh,
    const float* __restrict__ W_osx, const float* __restrict__ b_osx,
    float* __restrict__ out) {
  const int t = blockIdx.x;
  const int r = threadIdx.x;
  __shared__ __align__(16) float zt[64], ol[64], os[64];
  zt[r] = zseq[(size_t)t * 64 + r];
  __syncthreads();
  float a1 = b_olh[r], a2 = b_osh[r];
#pragma unroll
  for (int k = 0; k < 16; ++k) {
    float4 v  = ((const float4*)zt)[k];
    float4 w1 = ld4(W_olh + r * 64 + k * 4);
    float4 w2 = ld4(W_osh + r * 64 + k * 4);
    a1 = fmaf(w1.x, v.x, fmaf(w1.y, v.y, fmaf(w1.z, v.z, fmaf(w1.w, v.w, a1))));
    a2 = fmaf(w2.x, v.x, fmaf(w2.y, v.y, fmaf(w2.z, v.z, fmaf(w2.w, v.w, a2))));
  }
  ol[r] = fmaxf(a1, 0.f);
  os[r] = fmaxf(a2, 0.f);
  __syncthreads();
  const bool loc = (r < 32);
  const float* Wx = loc ? (W_olx + r * 64) : (W_osx + (r - 32) * 64);
  const float* xb = loc ? ol : os;
  float acc = loc ? b_olx[r] : b_osx[r - 32];
#pragma unroll
  for (int k = 0; k < 16; ++k) {
    float4 w = ld4(Wx + k * 4);
    float4 v = ((const float4*)xb)[k];
    acc = fmaf(w.x, v.x, fmaf(w.y, v.y, fmaf(w.z, v.z, fmaf(w.w, v.w, acc))));
  }
  out[(size_t)t * 64 + r] = fmaxf(acc, 0.f);
}

// out[n] = out[n mod 16384] for n >= 16384 (16384 = T*2X, power of two).
__global__ __launch_bounds__(256) void bcast_kernel(float* __restrict__ out) {
  const size_t total4 = (size_t)Bc * Tc * (2 * Xc) / 4;
  const size_t src4   = (size_t)Tc * (2 * Xc) / 4;
  const float4* s = (const float4*)out;
  float4* o = (float4*)out;
  size_t stride = (size_t)gridDim.x * blockDim.x;
  for (size_t i = (size_t)blockIdx.x * blockDim.x + threadIdx.x + src4;
       i < total4; i += stride) {
    o[i] = s[i & (src4 - 1)];
  }
}

extern "C" void kernel_launch(void* const* d_in, const int* in_sizes, int n_in,
                              void* d_out, int out_size, void* d_ws, size_t ws_size,
                              hipStream_t stream) {
  (void)in_sizes; (void)n_in; (void)d_ws; (void)ws_size; (void)out_size;
  const float* z0     = (const float*)d_in[1];
  const float* h0     = (const float*)d_in[2];
  const float* W_ih   = (const float*)d_in[3];
  const float* W_hh   = (const float*)d_in[4];
  const float* b_ih   = (const float*)d_in[5];
  const float* b_hh   = (const float*)d_in[6];
  const float* W_gzh  = (const float*)d_in[7];
  const float* b_gzh  = (const float*)d_in[8];
  const float* W_ghz  = (const float*)d_in[9];
  const float* b_ghz  = (const float*)d_in[10];
  const float* W_pzh  = (const float*)d_in[11];
  const float* b_pzh  = (const float*)d_in[12];
  const float* W_phz  = (const float*)d_in[13];
  const float* b_phz  = (const float*)d_in[14];
  const float* W_zloc = (const float*)d_in[15];
  const float* b_zloc = (const float*)d_in[16];
  const float* W_olh  = (const float*)d_in[19];
  const float* b_olh  = (const float*)d_in[20];
  const float* W_olx  = (const float*)d_in[21];
  const float* b_olx  = (const float*)d_in[22];
  const float* W_osh  = (const float*)d_in[23];
  const float* b_osh  = (const float*)d_in[24];
  const float* W_osx  = (const float*)d_in[25];
  const float* b_osx  = (const float*)d_in[26];
  float* out = (float*)d_out;

  float* zseq = out + (size_t)Tc * 2 * Xc;

  chain_kernel<<<1, 512, 0, stream>>>(
      z0, h0, W_ih, W_hh, b_ih, b_hh,
      W_gzh, b_gzh, W_ghz, b_ghz, W_pzh, b_pzh, W_phz, b_phz,
      W_zloc, b_zloc, zseq);

  obs_kernel<<<Tc, 64, 0, stream>>>(
      zseq, W_olh, b_olh, W_olx, b_olx, W_osh, b_osh, W_osx, b_osx, out);

  bcast_kernel<<<2048, 256, 0, stream>>>(out);
}